// Round 11
// baseline (248.879 us; speedup 1.0000x reference)
//
#include <hip/hip_runtime.h>
#include <hip/hip_bf16.h>

typedef __attribute__((ext_vector_type(8))) short bf16x8;
typedef __attribute__((ext_vector_type(4))) float f32x4;
typedef __attribute__((ext_vector_type(2))) float f32x2;
typedef unsigned short u16;
typedef unsigned int u32;

__device__ __forceinline__ u16 f2bf(float f){
  __hip_bfloat16 h = __float2bfloat16(f);
  return *reinterpret_cast<u16*>(&h);
}
__device__ __forceinline__ float bflo(u32 w){ return __uint_as_float(w << 16); }
__device__ __forceinline__ float bfhi(u32 w){ return __uint_as_float(w & 0xffff0000u); }
// HW packed f32->bf16 (RNE). Verified bit-compatible on this chip: R8's fully
// pack2bf-converted run produced identical absmax to the f2bf path.
__device__ __forceinline__ u32 pack2bf(float a, float b){
  u32 r;
  asm("v_cvt_pk_bf16_f32 %0, %1, %2" : "=v"(r) : "v"(a), "v"(b));
  return r;   // lo16=bf16(a), hi16=bf16(b) -> memory order a,b
}

// async global->LDS, 16B per lane. LDS dest is wave-uniform base + lane*16 (linear).
__device__ __forceinline__ void gload_lds16(const u16* g, u16* l){
  __builtin_amdgcn_global_load_lds(
      (__attribute__((address_space(1))) u32*)g,
      (__attribute__((address_space(3))) u32*)l, 16, 0, 0);
}

// Merged f32->bf16 convert for x / w_qkv / w_proj.
// w_qkv rows 0..767 (q-projection rows) pre-scaled by ATT_SCALE=0.125 so the
// scores GEMM directly produces scaled logits.
__global__ __launch_bounds__(256) void cvt3_kernel(
    const float* __restrict__ s0, u16* __restrict__ d0, int n0,
    const float* __restrict__ s1, u16* __restrict__ d1, int n1,
    const float* __restrict__ s2, u16* __restrict__ d2, int n2)
{
  int i = blockIdx.x*256 + threadIdx.x;
  const float* s; u16* d; int idx; float sc = 1.f;
  if (i < n0){ s = s0; d = d0; idx = i; }
  else if (i < n0 + n1){
    idx = i - n0; s = s1; d = d1;
    if (idx < 768*192) sc = 0.125f;          // f4-index < 768 rows * 192 f4/row
  } else if (i < n0 + n1 + n2){
    idx = i - n0 - n1; s = s2; d = d2;
  } else return;
  float4 v = reinterpret_cast<const float4*>(s)[idx];
  uint2 o;
  o.x = pack2bf(v.x*sc, v.y*sc);
  o.y = pack2bf(v.z*sc, v.w*sc);
  reinterpret_cast<uint2*>(d)[idx] = o;
}

// C = A(MxK) * B(NxK)^T, A/B bf16 row-major, batched over blockIdx.z.
// Staging via global_load_lds width=16 into linear [rows][BK] LDS tiles.
// BK=32 (verified best: BK=64 regressed in R9).
// MODE 0: QKV scatter -> Q[B,H,N,D](C0), K[B,H,N,D](C1), Vt[B,H,D,N](C2)
// MODE 1: bf16 store, batch stride sC (scores)
// MODE 2: PV -> tmp[B,N,H,D] bf16 (z = b*12+h)
// MODE 3: fp32 store + bias (projection)
template<int BM, int BN, int BK, int MODE>
__global__ __launch_bounds__(256) void gemm_bt(
    const u16* __restrict__ A, const u16* __restrict__ B,
    void* __restrict__ C0, void* __restrict__ C1, void* __restrict__ C2,
    const float* __restrict__ bias,
    int M, int N, int K, int lda, int ldb, long sA, long sB, long sC)
{
  constexpr int LDT = BK;            // linear: required by global_load_lds
  constexpr int CB  = BK/8;          // 16B chunks per row
  __shared__ __align__(16) u16 As[BM*LDT];
  __shared__ __align__(16) u16 Bs[BN*LDT];
  const int z = blockIdx.z;
  const u16* Ab = A + (long)z * sA;
  const u16* Bb = B + (long)z * sB;
  const int bm = blockIdx.x * BM, bn = blockIdx.y * BN;
  const int tid = threadIdx.x, lane = tid & 63, wv = tid >> 6;
  constexpr int WM = BM/2, WN = BN/2, FM = WM/16, FN = WN/16;
  const int wm = (wv >> 1) * WM, wn = (wv & 1) * WN;
  const int quad = lane >> 4, cl = lane & 15;
  f32x4 acc[FM][FN];
  #pragma unroll
  for (int i=0;i<FM;i++)
    #pragma unroll
    for (int j=0;j<FN;j++){ f32x4 zr = {0.f,0.f,0.f,0.f}; acc[i][j] = zr; }
  constexpr int AIT = (BM*BK)/(8*256);
  constexpr int BIT = (BN*BK)/(8*256);

  for (int kb = 0; kb < K; kb += BK){
    __syncthreads();
    #pragma unroll
    for (int sL=0; sL<AIT; sL++){
      int e = tid + sL*256, r = e / CB, c8 = (e % CB) * 8;
      gload_lds16(Ab + (long)(bm + r)*lda + kb + c8, &As[e*8]);
    }
    #pragma unroll
    for (int sL=0; sL<BIT; sL++){
      int e = tid + sL*256, r = e / CB, c8 = (e % CB) * 8;
      gload_lds16(Bb + (long)(bn + r)*ldb + kb + c8, &Bs[e*8]);
    }
    __syncthreads();   // compiler drains vmcnt before barrier
    #pragma unroll
    for (int ks=0; ks<BK/32; ks++){
      bf16x8 af[FM], bfr[FN];
      #pragma unroll
      for (int i=0;i<FM;i++)
        af[i] = *reinterpret_cast<const bf16x8*>(&As[(wm + i*16 + cl)*LDT + ks*32 + quad*8]);
      #pragma unroll
      for (int j=0;j<FN;j++)
        bfr[j] = *reinterpret_cast<const bf16x8*>(&Bs[(wn + j*16 + cl)*LDT + ks*32 + quad*8]);
      #pragma unroll
      for (int i=0;i<FM;i++)
        #pragma unroll
        for (int j=0;j<FN;j++)
          acc[i][j] = __builtin_amdgcn_mfma_f32_16x16x32_bf16(af[i], bfr[j], acc[i][j], 0, 0, 0);
    }
  }

  #pragma unroll
  for (int i=0;i<FM;i++)
  #pragma unroll
  for (int j=0;j<FN;j++)
  #pragma unroll
  for (int r=0;r<4;r++){
    int gm = bm + wm + i*16 + quad*4 + r;
    int gn = bn + wn + j*16 + cl;
    float v = acc[i][j][r];
    if (MODE == 0){
      int b_ = gm >> 10, n_ = gm & 1023;
      int t3 = (gn >= 1536) ? 2 : ((gn >= 768) ? 1 : 0);
      int rem = gn - t3*768;
      int h = rem >> 6, d = rem & 63;
      u16 hv = f2bf(v);
      if (t3 == 0)      ((u16*)C0)[((long)((b_*12 + h)*1024 + n_))*64 + d] = hv;
      else if (t3 == 1) ((u16*)C1)[((long)((b_*12 + h)*1024 + n_))*64 + d] = hv;
      else              ((u16*)C2)[((long)((b_*12 + h)*64 + d))*1024 + n_] = hv;
    } else if (MODE == 1){
      ((u16*)C0)[(long)z*sC + (long)gm*N + gn] = f2bf(v);
    } else if (MODE == 2){
      int b_ = z / 12, h = z - b_*12;
      ((u16*)C0)[((long)((b_*1024 + gm)*12 + h))*64 + gn] = f2bf(v);
    } else {
      ((float*)C0)[(long)gm*N + gn] = v + bias[gn];
    }
  }
}

// Four waves per (b,n) row; each lane owns 4 m (thread t -> m = t*4..t*4+3) held as
// two f32x2 so the 12x12 mixes run on v_pk_fma_f32.
// NO max subtraction (logits bounded ~|3| by construction).
// exp2-domain: log2(e) folded into premix weights (SALU) -> raw v_exp_f32.
// Reduction: R6-proven shuffle butterfly + tiny redS (0 conflicts, VGPR~52).
// Stores: HW v_cvt_pk_bf16_f32 (saves ~200 VALU issues/thread vs RNE emulation).
__global__ __launch_bounds__(256) void mix_kernel(
    u16* __restrict__ S, const float* __restrict__ mask,
    const float* __restrict__ w_pre, const float* __restrict__ w_post)
{
  const int bid = blockIdx.x;            // 0..4095 = b*1024 + n
  const int b = bid >> 10, n = bid & 1023;
  const int t = threadIdx.x;             // 0..255
  const int wv = t >> 6, lane = t & 63;
  const int m0 = t * 4;
  const long base0 = (((long)(b*12))*1024 + n) * 1024;   // h=0 plane, row n
  constexpr float LOG2E = 1.44269504f;

  // ---- issue all VMEM up front: 12 S-plane reads (8B) + mask (16B) ----
  uint2 raw[12];
  #pragma unroll
  for (int h=0; h<12; h++)
    raw[h] = *reinterpret_cast<const uint2*>(S + base0 + (long)h*1024*1024 + m0);
  float4 mk4 = *reinterpret_cast<const float4*>(mask + ((long)(b*1024 + n))*1024 + m0);

  // ---- pre-mix in log2 domain: smix = LOG2E*(rs*mask + sum_h w_pre*S_h) ----
  f32x2 smix[12][2];
  {
    f32x2 mkA = {mk4.x, mk4.y}, mkB = {mk4.z, mk4.w};
    #pragma unroll
    for (int g=0; g<12; g++){
      float rs = 0.f;
      #pragma unroll
      for (int h=0; h<12; h++) rs += w_pre[g*12 + h];   // uniform -> SALU
      rs *= LOG2E;                                      // SALU, free
      smix[g][0] = rs * mkA;
      smix[g][1] = rs * mkB;
    }
  }
  #pragma unroll
  for (int h=0; h<12; h++){
    f32x2 s0 = {bflo(raw[h].x), bfhi(raw[h].x)};
    f32x2 s1 = {bflo(raw[h].y), bfhi(raw[h].y)};
    #pragma unroll
    for (int g=0; g<12; g++){
      float w = w_pre[g*12 + h] * LOG2E;                // uniform -> SALU
      smix[g][0] += w * s0;
      smix[g][1] += w * s1;
    }
  }

  // ---- exp2 + sum (no max pass) ----
  __shared__ float redS[12][4];
  float L[12];
  #pragma unroll
  for (int g=0; g<12; g++){
    float e0, e1, e2, e3;
    asm("v_exp_f32 %0, %1" : "=v"(e0) : "v"(smix[g][0][0]));
    asm("v_exp_f32 %0, %1" : "=v"(e1) : "v"(smix[g][0][1]));
    asm("v_exp_f32 %0, %1" : "=v"(e2) : "v"(smix[g][1][0]));
    asm("v_exp_f32 %0, %1" : "=v"(e3) : "v"(smix[g][1][1]));
    smix[g][0][0]=e0; smix[g][0][1]=e1; smix[g][1][0]=e2; smix[g][1][1]=e3;
    L[g] = (e0 + e1) + (e2 + e3);
  }
  #pragma unroll
  for (int off=32; off>0; off>>=1)
    #pragma unroll
    for (int g=0; g<12; g++) L[g] += __shfl_xor(L[g], off);
  if (lane == 0){
    #pragma unroll
    for (int g=0; g<12; g++) redS[g][wv] = L[g];
  }
  __syncthreads();
  #pragma unroll
  for (int g=0; g<12; g++){
    float Lt = (redS[g][0] + redS[g][1]) + (redS[g][2] + redS[g][3]);
    float inv;
    asm("v_rcp_f32 %0, %1" : "=v"(inv) : "v"(Lt));   // ~1ulp, << bf16 noise
    smix[g][0] *= inv;
    smix[g][1] *= inv;
  }

  // ---- post-mix + packed bf16 store, streamed per output head ----
  #pragma unroll
  for (int h=0; h<12; h++){
    f32x2 o0, o1;
    {
      float w = w_post[h*12];
      o0 = w * smix[0][0];
      o1 = w * smix[0][1];
    }
    #pragma unroll
    for (int g=1; g<12; g++){
      float w = w_post[h*12 + g];
      o0 += w * smix[g][0];
      o1 += w * smix[g][1];
    }
    uint2 st;
    st.x = pack2bf(o0[0], o0[1]);
    st.y = pack2bf(o1[0], o1[1]);
    *reinterpret_cast<uint2*>(S + base0 + (long)h*1024*1024 + m0) = st;
  }
}

extern "C" void kernel_launch(void* const* d_in, const int* in_sizes, int n_in,
                              void* d_out, int out_size, void* d_ws, size_t ws_size,
                              hipStream_t stream)
{
  const float* x      = (const float*)d_in[0];
  const float* mask   = (const float*)d_in[1];
  const float* w_qkv  = (const float*)d_in[2];
  const float* w_proj = (const float*)d_in[3];
  const float* b_proj = (const float*)d_in[4];
  const float* w_pre  = (const float*)d_in[5];
  const float* w_post = (const float*)d_in[6];
  float* out = (float*)d_out;

  u16* xb     = (u16*)d_ws;
  u16* wqkvb  = xb     + 4096l*768;
  u16* wprojb = wqkvb  + 2304l*768;
  u16* Qb     = wprojb + 768l*768;
  u16* Kb     = Qb     + 48l*1024*64;
  u16* Vtb    = Kb     + 48l*1024*64;
  u16* tmpb   = Vtb    + 48l*1024*64;
  u16* Sb     = tmpb   + 4096l*768;
  size_t need = ((size_t)(Sb - xb) + 48ul*1024*1024) * sizeof(u16);
  if (ws_size < need) return;   // insufficient scratch: fail visibly

  const int n0 = 4096*768/4, n1 = 2304*768/4, n2 = 768*768/4;
  cvt3_kernel<<<(n0+n1+n2 + 255)/256, 256, 0, stream>>>(x, xb, n0, w_qkv, wqkvb, n1,
                                                        w_proj, wprojb, n2);

  dim3 gq(4096/128, 2304/128, 1);
  gemm_bt<128,128,32,0><<<gq, 256, 0, stream>>>(xb, wqkvb, Qb, Kb, Vtb, nullptr,
      4096, 2304, 768, 768, 768, 0, 0, 0);

  dim3 gs(1024/128, 1024/128, 48);
  gemm_bt<128,128,32,1><<<gs, 256, 0, stream>>>(Qb, Kb, Sb, nullptr, nullptr, nullptr,
      1024, 1024, 64, 64, 64, 1024l*64, 1024l*64, 1024l*1024);

  mix_kernel<<<4096, 256, 0, stream>>>(Sb, mask, w_pre, w_post);

  dim3 gp(1024/128, 1, 48);
  gemm_bt<128,64,32,2><<<gp, 256, 0, stream>>>(Sb, Vtb, tmpb, nullptr, nullptr, nullptr,
      1024, 64, 1024, 1024, 1024, 1024l*1024, 64l*1024, 0);

  dim3 go(4096/128, 768/128, 1);
  gemm_bt<128,128,32,3><<<go, 256, 0, stream>>>(tmpb, wprojb, out, nullptr, nullptr, b_proj,
      4096, 768, 768, 768, 768, 0, 0, 0);
}

// Round 12
// 242.655 us; speedup vs baseline: 1.0256x; 1.0256x over previous
//
#include <hip/hip_runtime.h>
#include <hip/hip_bf16.h>

typedef __attribute__((ext_vector_type(8))) short bf16x8;
typedef __attribute__((ext_vector_type(4))) float f32x4;
typedef __attribute__((ext_vector_type(2))) float f32x2;
typedef unsigned short u16;
typedef unsigned int u32;

__device__ __forceinline__ u16 f2bf(float f){
  __hip_bfloat16 h = __float2bfloat16(f);
  return *reinterpret_cast<u16*>(&h);
}
__device__ __forceinline__ float bflo(u32 w){ return __uint_as_float(w << 16); }
__device__ __forceinline__ float bfhi(u32 w){ return __uint_as_float(w & 0xffff0000u); }

// async global->LDS, 16B per lane. LDS dest is wave-uniform base + lane*16 (linear).
__device__ __forceinline__ void gload_lds16(const u16* g, u16* l){
  __builtin_amdgcn_global_load_lds(
      (__attribute__((address_space(1))) u32*)g,
      (__attribute__((address_space(3))) u32*)l, 16, 0, 0);
}

// Merged f32->bf16 convert for x / w_qkv / w_proj.
// w_qkv rows 0..767 (q-projection rows) pre-scaled by ATT_SCALE=0.125 so the
// scores GEMM directly produces scaled logits.
__global__ __launch_bounds__(256) void cvt3_kernel(
    const float* __restrict__ s0, u16* __restrict__ d0, int n0,
    const float* __restrict__ s1, u16* __restrict__ d1, int n1,
    const float* __restrict__ s2, u16* __restrict__ d2, int n2)
{
  int i = blockIdx.x*256 + threadIdx.x;
  const float* s; u16* d; int idx; float sc = 1.f;
  if (i < n0){ s = s0; d = d0; idx = i; }
  else if (i < n0 + n1){
    idx = i - n0; s = s1; d = d1;
    if (idx < 768*192) sc = 0.125f;          // f4-index < 768 rows * 192 f4/row
  } else if (i < n0 + n1 + n2){
    idx = i - n0 - n1; s = s2; d = d2;
  } else return;
  float4 v = reinterpret_cast<const float4*>(s)[idx];
  ushort4 o;
  o.x = f2bf(v.x*sc); o.y = f2bf(v.y*sc); o.z = f2bf(v.z*sc); o.w = f2bf(v.w*sc);
  reinterpret_cast<ushort4*>(d)[idx] = o;
}

// C = A(MxK) * B(NxK)^T, A/B bf16 row-major, batched over blockIdx.z.
// Staging via global_load_lds width=16 into linear [rows][BK] LDS tiles.
// BK=32 (verified best; BK=64 regressed in R9).
// S layout is interleaved [b][n][h][m] (mix locality): MODE 1 stores it,
// MODE 2 reads it (A-base special-cased, lda=12288).
// MODE 0: QKV scatter -> Q[B,H,N,D](C0), K[B,H,N,D](C1), Vt[B,H,D,N](C2)
// MODE 1: bf16 store -> S[b][n][h][m]   (z = b*12+h)
// MODE 2: PV -> tmp[B,N,H,D] bf16       (z = b*12+h, A = S interleaved)
// MODE 3: fp32 store + bias (projection)
template<int BM, int BN, int BK, int MODE>
__global__ __launch_bounds__(256) void gemm_bt(
    const u16* __restrict__ A, const u16* __restrict__ B,
    void* __restrict__ C0, void* __restrict__ C1, void* __restrict__ C2,
    const float* __restrict__ bias,
    int M, int N, int K, int lda, int ldb, long sA, long sB, long sC)
{
  constexpr int LDT = BK;            // linear: required by global_load_lds
  constexpr int CB  = BK/8;          // 16B chunks per row
  __shared__ __align__(16) u16 As[BM*LDT];
  __shared__ __align__(16) u16 Bs[BN*LDT];
  const int z = blockIdx.z;
  const u16* Ab;
  if (MODE == 2){
    int b_ = z / 12, h_ = z - b_*12;
    Ab = A + (long)b_*(1024l*12*1024) + (long)h_*1024;   // S[b][n][h][m], lda=12288
  } else {
    Ab = A + (long)z * sA;
  }
  const u16* Bb = B + (long)z * sB;
  const int bm = blockIdx.x * BM, bn = blockIdx.y * BN;
  const int tid = threadIdx.x, lane = tid & 63, wv = tid >> 6;
  constexpr int WM = BM/2, WN = BN/2, FM = WM/16, FN = WN/16;
  const int wm = (wv >> 1) * WM, wn = (wv & 1) * WN;
  const int quad = lane >> 4, cl = lane & 15;
  f32x4 acc[FM][FN];
  #pragma unroll
  for (int i=0;i<FM;i++)
    #pragma unroll
    for (int j=0;j<FN;j++){ f32x4 zr = {0.f,0.f,0.f,0.f}; acc[i][j] = zr; }
  constexpr int AIT = (BM*BK)/(8*256);
  constexpr int BIT = (BN*BK)/(8*256);

  for (int kb = 0; kb < K; kb += BK){
    __syncthreads();
    #pragma unroll
    for (int sL=0; sL<AIT; sL++){
      int e = tid + sL*256, r = e / CB, c8 = (e % CB) * 8;
      gload_lds16(Ab + (long)(bm + r)*lda + kb + c8, &As[e*8]);
    }
    #pragma unroll
    for (int sL=0; sL<BIT; sL++){
      int e = tid + sL*256, r = e / CB, c8 = (e % CB) * 8;
      gload_lds16(Bb + (long)(bn + r)*ldb + kb + c8, &Bs[e*8]);
    }
    __syncthreads();   // compiler drains vmcnt before barrier
    #pragma unroll
    for (int ks=0; ks<BK/32; ks++){
      bf16x8 af[FM], bfr[FN];
      #pragma unroll
      for (int i=0;i<FM;i++)
        af[i] = *reinterpret_cast<const bf16x8*>(&As[(wm + i*16 + cl)*LDT + ks*32 + quad*8]);
      #pragma unroll
      for (int j=0;j<FN;j++)
        bfr[j] = *reinterpret_cast<const bf16x8*>(&Bs[(wn + j*16 + cl)*LDT + ks*32 + quad*8]);
      #pragma unroll
      for (int i=0;i<FM;i++)
        #pragma unroll
        for (int j=0;j<FN;j++)
          acc[i][j] = __builtin_amdgcn_mfma_f32_16x16x32_bf16(af[i], bfr[j], acc[i][j], 0, 0, 0);
    }
  }

  #pragma unroll
  for (int i=0;i<FM;i++)
  #pragma unroll
  for (int j=0;j<FN;j++)
  #pragma unroll
  for (int r=0;r<4;r++){
    int gm = bm + wm + i*16 + quad*4 + r;
    int gn = bn + wn + j*16 + cl;
    float v = acc[i][j][r];
    if (MODE == 0){
      int b_ = gm >> 10, n_ = gm & 1023;
      int t3 = (gn >= 1536) ? 2 : ((gn >= 768) ? 1 : 0);
      int rem = gn - t3*768;
      int h = rem >> 6, d = rem & 63;
      u16 hv = f2bf(v);
      if (t3 == 0)      ((u16*)C0)[((long)((b_*12 + h)*1024 + n_))*64 + d] = hv;
      else if (t3 == 1) ((u16*)C1)[((long)((b_*12 + h)*1024 + n_))*64 + d] = hv;
      else              ((u16*)C2)[((long)((b_*12 + h)*64 + d))*1024 + n_] = hv;
    } else if (MODE == 1){
      int b_ = z / 12, h_ = z - b_*12;
      ((u16*)C0)[((long)((b_*1024 + gm)*12 + h_))*1024 + gn] = f2bf(v);
    } else if (MODE == 2){
      int b_ = z / 12, h = z - b_*12;
      ((u16*)C0)[((long)((b_*1024 + gm)*12 + h))*64 + gn] = f2bf(v);
    } else {
      ((float*)C0)[(long)gm*N + gn] = v + bias[gn];
    }
  }
}

// Four waves per (b,n) row; each lane owns 4 m (thread t -> m = t*4..t*4+3) held as
// two f32x2 so the 12x12 mixes run on v_pk_fma_f32.
// NO max subtraction (logits bounded ~|3| by construction).
// S interleaved [b][n][h][m]: the 12 h-streams for a row are 2KB apart (one 24KB
// contiguous window per block) instead of 2MB -> DRAM/TLB/L2 locality.
// Exactly the R6-proven structure otherwise (no inline-asm exp/cvt: R11 showed
// asm blocks inflate VGPR 52->84 and cost 6.5us).
__global__ __launch_bounds__(256) void mix_kernel(
    u16* __restrict__ S, const float* __restrict__ mask,
    const float* __restrict__ w_pre, const float* __restrict__ w_post)
{
  const int bid = blockIdx.x;            // 0..4095 = b*1024 + n
  const int b = bid >> 10, n = bid & 1023;
  const int t = threadIdx.x;             // 0..255
  const int wv = t >> 6, lane = t & 63;
  const int m0 = t * 4;
  const long base0 = ((long)(b*1024 + n)) * 12 * 1024;   // row window, h stride 1024

  // ---- issue all VMEM up front: 12 S-plane reads (8B) + mask (16B) ----
  uint2 raw[12];
  #pragma unroll
  for (int h=0; h<12; h++)
    raw[h] = *reinterpret_cast<const uint2*>(S + base0 + h*1024 + m0);
  float4 mk4 = *reinterpret_cast<const float4*>(mask + ((long)(b*1024 + n))*1024 + m0);

  // ---- pre-mix: smix[g] = (sum_h w_pre[g,h])*mask + sum_h w_pre[g,h]*S_h ----
  f32x2 smix[12][2];
  {
    f32x2 mkA = {mk4.x, mk4.y}, mkB = {mk4.z, mk4.w};
    #pragma unroll
    for (int g=0; g<12; g++){
      float rs = 0.f;
      #pragma unroll
      for (int h=0; h<12; h++) rs += w_pre[g*12 + h];   // uniform -> SALU
      smix[g][0] = rs * mkA;
      smix[g][1] = rs * mkB;
    }
  }
  #pragma unroll
  for (int h=0; h<12; h++){
    f32x2 s0 = {bflo(raw[h].x), bfhi(raw[h].x)};
    f32x2 s1 = {bflo(raw[h].y), bfhi(raw[h].y)};
    #pragma unroll
    for (int g=0; g<12; g++){
      float w = w_pre[g*12 + h];
      smix[g][0] += w * s0;
      smix[g][1] += w * s1;
    }
  }

  // ---- exp + sum (no max pass) ----
  __shared__ float redS[12][4];
  float L[12];
  #pragma unroll
  for (int g=0; g<12; g++){
    float e0 = __expf(smix[g][0][0]);
    float e1 = __expf(smix[g][0][1]);
    float e2 = __expf(smix[g][1][0]);
    float e3 = __expf(smix[g][1][1]);
    smix[g][0][0]=e0; smix[g][0][1]=e1; smix[g][1][0]=e2; smix[g][1][1]=e3;
    L[g] = (e0 + e1) + (e2 + e3);
  }
  #pragma unroll
  for (int off=32; off>0; off>>=1)
    #pragma unroll
    for (int g=0; g<12; g++) L[g] += __shfl_xor(L[g], off);
  if (lane == 0){
    #pragma unroll
    for (int g=0; g<12; g++) redS[g][wv] = L[g];
  }
  __syncthreads();
  #pragma unroll
  for (int g=0; g<12; g++){
    float Lt = (redS[g][0] + redS[g][1]) + (redS[g][2] + redS[g][3]);
    float inv;
    asm("v_rcp_f32 %0, %1" : "=v"(inv) : "v"(Lt));   // ~1ulp, << bf16 noise
    smix[g][0] *= inv;
    smix[g][1] *= inv;
  }

  // ---- post-mix + packed bf16 store, streamed per output head ----
  #pragma unroll
  for (int h=0; h<12; h++){
    f32x2 o0, o1;
    {
      float w = w_post[h*12];
      o0 = w * smix[0][0];
      o1 = w * smix[0][1];
    }
    #pragma unroll
    for (int g=1; g<12; g++){
      float w = w_post[h*12 + g];
      o0 += w * smix[g][0];
      o1 += w * smix[g][1];
    }
    ushort4 st;
    st.x = f2bf(o0[0]); st.y = f2bf(o0[1]);
    st.z = f2bf(o1[0]); st.w = f2bf(o1[1]);
    *reinterpret_cast<ushort4*>(S + base0 + h*1024 + m0) = st;
  }
}

extern "C" void kernel_launch(void* const* d_in, const int* in_sizes, int n_in,
                              void* d_out, int out_size, void* d_ws, size_t ws_size,
                              hipStream_t stream)
{
  const float* x      = (const float*)d_in[0];
  const float* mask   = (const float*)d_in[1];
  const float* w_qkv  = (const float*)d_in[2];
  const float* w_proj = (const float*)d_in[3];
  const float* b_proj = (const float*)d_in[4];
  const float* w_pre  = (const float*)d_in[5];
  const float* w_post = (const float*)d_in[6];
  float* out = (float*)d_out;

  u16* xb     = (u16*)d_ws;
  u16* wqkvb  = xb     + 4096l*768;
  u16* wprojb = wqkvb  + 2304l*768;
  u16* Qb     = wprojb + 768l*768;
  u16* Kb     = Qb     + 48l*1024*64;
  u16* Vtb    = Kb     + 48l*1024*64;
  u16* tmpb   = Vtb    + 48l*1024*64;
  u16* Sb     = tmpb   + 4096l*768;
  size_t need = ((size_t)(Sb - xb) + 48ul*1024*1024) * sizeof(u16);
  if (ws_size < need) return;   // insufficient scratch: fail visibly

  const int n0 = 4096*768/4, n1 = 2304*768/4, n2 = 768*768/4;
  cvt3_kernel<<<(n0+n1+n2 + 255)/256, 256, 0, stream>>>(x, xb, n0, w_qkv, wqkvb, n1,
                                                        w_proj, wprojb, n2);

  dim3 gq(4096/128, 2304/128, 1);
  gemm_bt<128,128,32,0><<<gq, 256, 0, stream>>>(xb, wqkvb, Qb, Kb, Vtb, nullptr,
      4096, 2304, 768, 768, 768, 0, 0, 0);

  dim3 gs(1024/128, 1024/128, 48);
  gemm_bt<128,128,32,1><<<gs, 256, 0, stream>>>(Qb, Kb, Sb, nullptr, nullptr, nullptr,
      1024, 1024, 64, 64, 64, 1024l*64, 1024l*64, 0);

  mix_kernel<<<4096, 256, 0, stream>>>(Sb, mask, w_pre, w_post);

  dim3 gp(1024/64, 1, 48);
  gemm_bt<64,64,32,2><<<gp, 256, 0, stream>>>(Sb, Vtb, tmpb, nullptr, nullptr, nullptr,
      1024, 64, 1024, 12288, 1024, 0, 64l*1024, 0);

  dim3 go(4096/128, 768/128, 1);
  gemm_bt<128,128,32,3><<<go, 256, 0, stream>>>(tmpb, wprojb, out, nullptr, nullptr, b_proj,
      4096, 768, 768, 768, 768, 0, 0, 0);
}